// Round 5
// baseline (251.850 us; speedup 1.0000x reference)
//
#include <hip/hip_runtime.h>

// CausalAttention: B=4, S=2048, D=1024, single head over full D.
// R5: all GEMMs move to a 3-stage software-pipelined K-loop (AITER pattern):
//   per iter: asm("s_waitcnt vmcnt(4); s_barrier")  -- wait only own 4 loads
//   of the current tile, prefetch tile t+2 into stage (t+2)%3 AFTER the
//   barrier (which proves stage (t-1)%3 is no longer being read).
// Loads stay in flight across the barrier (~2 iters flight) instead of the
// m97 structure's full vmcnt(0) drain per iter (R4: MfmaUtil 29%, 57% idle).
// BK=32, 48 KB LDS (3 stages x 8 KB x {A,B}), XOR bank swizzle (R2: 0 confl).

typedef __attribute__((ext_vector_type(8))) _Float16 f16x8;
typedef __attribute__((ext_vector_type(4))) _Float16 f16x4;
typedef __attribute__((ext_vector_type(4))) float f32x4;

#define NB   4
#define SEQ  2048
#define DIM  1024
#define SCL  0.03125f   // 1/sqrt(1024)
#define PBATCH (136 * 16384)   // packed P elems per batch (tri(16) tiles)

__device__ __forceinline__ void gll16(const _Float16* g, _Float16* l) {
  __builtin_amdgcn_global_load_lds(
      (__attribute__((address_space(1))) void*)(g),
      (__attribute__((address_space(3))) void*)(l), 16, 0, 0);
}

// 3-stage pipelined core. As/Bs are [3][128][32] fp16 (24 KB each).
// Per wave per tile: 4 gll16 (2 A-lines + 2 B-lines of 1 KB).
__device__ __forceinline__ void gemm_pipe(
    const _Float16* __restrict__ A, int lda,
    const _Float16* __restrict__ Bm, int ldb,
    int K, _Float16* As, _Float16* Bs, f32x4 acc[4][4])
{
  const int t    = threadIdx.x;
  const int wv   = t >> 6;
  const int ln   = t & 63;
  const int lr   = ln & 15;
  const int lq   = ln >> 4;
  const int row0 = t >> 2;
  const int colb = (((t & 3) ^ ((row0 >> 1) & 3)) * 8);  // swizzled src chunk

  const _Float16* ga0 = A  + row0 * lda + colb;
  const _Float16* ga1 = A  + (64 + row0) * lda + colb;
  const _Float16* gb0 = Bm + row0 * ldb + colb;
  const _Float16* gb1 = Bm + (64 + row0) * ldb + colb;
  const int swzr = (lr >> 1) & 3;
  const int aoff = (((wv & 1) * 64) + lr) * 32 + ((lq ^ swzr) * 8);
  const int boff = (((wv >> 1) * 64) + lr) * 32 + ((lq ^ swzr) * 8);

  const int nt = K >> 5;   // tiles of BK=32 (>=4 in all call sites)

#define STAGE_LOAD(tile, s)                                   \
  do {                                                        \
    const int k0_ = (tile) * 32;                              \
    _Float16* a_ = As + (s) * 4096;                           \
    _Float16* b_ = Bs + (s) * 4096;                           \
    gll16(ga0 + k0_, a_ + wv * 512);                          \
    gll16(ga1 + k0_, a_ + 2048 + wv * 512);                   \
    gll16(gb0 + k0_, b_ + wv * 512);                          \
    gll16(gb1 + k0_, b_ + 2048 + wv * 512);                   \
  } while (0)

  STAGE_LOAD(0, 0);
  STAGE_LOAD(1, 1);

  for (int tt = 0; tt < nt; ++tt) {
    const int s = tt % 3;
    // Wait only for OWN 4 loads of tile tt (leave tile tt+1's 4 in flight),
    // then barrier: every wave has thus drained its stage-s writes, and all
    // waves are past their reads of stage (tt-1)%3 -> safe to overwrite.
    asm volatile("s_waitcnt vmcnt(4)\n\ts_barrier" ::: "memory");

    const _Float16* pa = As + s * 4096 + aoff;
    const _Float16* pb = Bs + s * 4096 + boff;
    f16x8 af[4], bf[4];
#pragma unroll
    for (int mi = 0; mi < 4; ++mi) af[mi] = *(const f16x8*)(pa + mi * 512);
#pragma unroll
    for (int ni = 0; ni < 4; ++ni) bf[ni] = *(const f16x8*)(pb + ni * 512);

    // prefetch tile tt+2 into stage (tt+2)%3 == (tt-1)%3 (clamp near end;
    // duplicate loads into a dead stage are harmless, addresses in-bounds)
    const int nxt = (tt + 2 < nt) ? tt + 2 : nt - 1;
    STAGE_LOAD(nxt, (tt + 2) % 3);

#pragma unroll
    for (int mi = 0; mi < 4; ++mi)
#pragma unroll
      for (int ni = 0; ni < 4; ++ni)
        acc[mi][ni] = __builtin_amdgcn_mfma_f32_16x16x32_f16(af[mi], bf[ni], acc[mi][ni], 0, 0, 0);
  }
#undef STAGE_LOAD
}

// one kernel converts x, Wq, Wk, Wv (blockIdx.y selects segment)
__global__ __launch_bounds__(256) void cvt_all(
    const float* __restrict__ x, const float* __restrict__ Wq,
    const float* __restrict__ Wk, const float* __restrict__ Wv,
    _Float16* __restrict__ xb, _Float16* __restrict__ Wb)
{
  const float* src; _Float16* dst; int n;
  const int M1 = 1024 * 1024;
  switch (blockIdx.y) {
    case 0: src = x;  dst = xb;          n = NB * SEQ * DIM; break;
    case 1: src = Wq; dst = Wb;          n = M1; break;
    case 2: src = Wk; dst = Wb + M1;     n = M1; break;
    default: src = Wv; dst = Wb + 2*M1;  n = M1; break;
  }
  int i = (blockIdx.x * 256 + threadIdx.x) * 4;
  const int stride = gridDim.x * 256 * 4;
  for (; i < n; i += stride) {
    const float4 v = *(const float4*)(src + i);
    f16x4 o;
    o.x = (_Float16)v.x; o.y = (_Float16)v.y; o.z = (_Float16)v.z; o.w = (_Float16)v.w;
    *(f16x4*)(dst + i) = o;
  }
}

// z=0: Q -> Qb; z=1: K -> Kb; z=2: V -> Vt [b][d][s] (transposed)
__global__ __launch_bounds__(256, 2) void qkv_gemm(
    const _Float16* __restrict__ xb, const _Float16* __restrict__ Wb,
    const float* __restrict__ bq, const float* __restrict__ bk,
    const float* __restrict__ bv,
    _Float16* __restrict__ Qb, _Float16* __restrict__ Kb, _Float16* __restrict__ Vt)
{
  __shared__ _Float16 As[3 * 4096];
  __shared__ _Float16 Bs[3 * 4096];
  const int m0 = blockIdx.x * 128;
  const int n0 = blockIdx.y * 128;
  const int z  = blockIdx.z;
  f32x4 acc[4][4];
#pragma unroll
  for (int mi = 0; mi < 4; ++mi)
#pragma unroll
    for (int ni = 0; ni < 4; ++ni) acc[mi][ni] = {0.f, 0.f, 0.f, 0.f};

  gemm_pipe(xb + (size_t)m0 * DIM, DIM,
            Wb + (size_t)z * DIM * DIM + (size_t)n0 * DIM, DIM,
            DIM, As, Bs, acc);

  const int t = threadIdx.x, wv = t >> 6, ln = t & 63, lr = ln & 15, lq = ln >> 4;
  const int wm = wv & 1, wn = wv >> 1;
  const float* bias = (z == 0) ? bq : (z == 1) ? bk : bv;
  if (z < 2) {
    _Float16* O = (z == 0) ? Qb : Kb;
#pragma unroll
    for (int ni = 0; ni < 4; ++ni) {
      const int col = n0 + wn * 64 + ni * 16 + lr;
      const float bb = bias[col];
#pragma unroll
      for (int mi = 0; mi < 4; ++mi) {
        const int r0 = m0 + wm * 64 + mi * 16 + lq * 4;
#pragma unroll
        for (int r = 0; r < 4; ++r)
          O[(size_t)(r0 + r) * DIM + col] = (_Float16)(acc[mi][ni][r] + bb);
      }
    }
  } else {
#pragma unroll
    for (int ni = 0; ni < 4; ++ni) {
      const int col = n0 + wn * 64 + ni * 16 + lr;
      const float bb = bias[col];
#pragma unroll
      for (int mi = 0; mi < 4; ++mi) {
        const int r0 = m0 + wm * 64 + mi * 16 + lq * 4;
        const int b = r0 >> 11, s = r0 & 2047;
        f16x4 pk;
#pragma unroll
        for (int r = 0; r < 4; ++r) pk[r] = (_Float16)(acc[mi][ni][r] + bb);
        *(f16x4*)(Vt + (size_t)b * DIM * SEQ + (size_t)col * SEQ + s) = pk;
      }
    }
  }
}

// Fused QK^T + exp + row-sum. Grid x = 136 lower-tri tiles, y = batch.
__global__ __launch_bounds__(256, 2) void qk_gemm(
    const _Float16* __restrict__ Qb, const _Float16* __restrict__ Kb,
    _Float16* __restrict__ Pm, float* __restrict__ lsum)
{
  const int idx = blockIdx.x;
  int qt = 0;
  while ((qt + 1) * (qt + 2) / 2 <= idx) ++qt;
  const int kt = idx - qt * (qt + 1) / 2;
  const int q0 = qt * 128, k0 = kt * 128, b = blockIdx.y;

  __shared__ _Float16 As[3 * 4096];
  __shared__ _Float16 Bs[3 * 4096];
  f32x4 acc[4][4];
#pragma unroll
  for (int mi = 0; mi < 4; ++mi)
#pragma unroll
    for (int ni = 0; ni < 4; ++ni) acc[mi][ni] = {0.f, 0.f, 0.f, 0.f};

  const _Float16* Qp = Qb + (size_t)b * SEQ * DIM + (size_t)q0 * DIM;
  const _Float16* Kp = Kb + (size_t)b * SEQ * DIM + (size_t)k0 * DIM;
  gemm_pipe(Qp, DIM, Kp, DIM, DIM, As, Bs, acc);

  const int t = threadIdx.x, wv = t >> 6, ln = t & 63, lr = ln & 15, lq = ln >> 4;
  const int wm = wv & 1, wn = wv >> 1;
  const int ldp = (qt + 1) * 128;
  _Float16* scr = Pm + (size_t)b * PBATCH + (size_t)(qt * (qt + 1) / 2) * 16384;
  float* lrow = lsum + b * SEQ;

  float es[4][4];
#pragma unroll
  for (int mi = 0; mi < 4; ++mi)
#pragma unroll
    for (int r = 0; r < 4; ++r) es[mi][r] = 0.f;

#pragma unroll
  for (int ni = 0; ni < 4; ++ni) {
    const int col = k0 + wn * 64 + ni * 16 + lr;
#pragma unroll
    for (int mi = 0; mi < 4; ++mi) {
      const int r0 = q0 + wm * 64 + mi * 16 + lq * 4;
#pragma unroll
      for (int r = 0; r < 4; ++r) {
        const int row = r0 + r;
        const float s = acc[mi][ni][r] * SCL;
        const float e = (col <= row) ? __expf(fminf(s, 10.f)) : 0.f;
        scr[(size_t)(row - q0) * ldp + col] = (_Float16)e;
        es[mi][r] += e;
      }
    }
  }
#pragma unroll
  for (int mi = 0; mi < 4; ++mi)
#pragma unroll
    for (int r = 0; r < 4; ++r) {
      float v = es[mi][r];
#pragma unroll
      for (int off = 1; off < 16; off <<= 1) v += __shfl_xor(v, off, 64);
      if (lr == 0) {
        const int row = q0 + wm * 64 + mi * 16 + lq * 4 + r;
        atomicAdd(&lrow[row], v);
      }
    }
}

// out[b][q][d] = (sum_k e[q][k] * Vt[b][d][k]) / l[b][q]; qt big-first.
__global__ __launch_bounds__(256, 2) void pv_gemm(
    const _Float16* __restrict__ Pm, const _Float16* __restrict__ Vt,
    const float* __restrict__ lsum, float* __restrict__ out)
{
  __shared__ _Float16 As[3 * 4096];
  __shared__ _Float16 Bs[3 * 4096];
  const int qt = 15 - blockIdx.x;
  const int q0 = qt * 128;
  const int d0 = blockIdx.y * 128;
  const int b  = blockIdx.z;
  const int K  = (qt + 1) * 128;
  f32x4 acc[4][4];
#pragma unroll
  for (int mi = 0; mi < 4; ++mi)
#pragma unroll
    for (int ni = 0; ni < 4; ++ni) acc[mi][ni] = {0.f, 0.f, 0.f, 0.f};

  const _Float16* Pp = Pm + (size_t)b * PBATCH + (size_t)(qt * (qt + 1) / 2) * 16384;
  const _Float16* Vp = Vt + (size_t)b * DIM * SEQ + (size_t)d0 * SEQ;
  gemm_pipe(Pp, K, Vp, SEQ, K, As, Bs, acc);

  const int t = threadIdx.x, wv = t >> 6, ln = t & 63, lr = ln & 15, lq = ln >> 4;
  const int wm = wv & 1, wn = wv >> 1;
  float* O = out + (size_t)b * SEQ * DIM;
  const float* lrow = lsum + b * SEQ;
#pragma unroll
  for (int mi = 0; mi < 4; ++mi) {
    const int r0 = q0 + wm * 64 + mi * 16 + lq * 4;
    const float4 lv = *(const float4*)(lrow + r0);
    const float inv[4] = {1.f / lv.x, 1.f / lv.y, 1.f / lv.z, 1.f / lv.w};
#pragma unroll
    for (int ni = 0; ni < 4; ++ni) {
      const int col = d0 + wn * 64 + ni * 16 + lr;
#pragma unroll
      for (int r = 0; r < 4; ++r)
        O[(size_t)(r0 + r) * DIM + col] = acc[mi][ni][r] * inv[r];
    }
  }
}

extern "C" void kernel_launch(void* const* d_in, const int* in_sizes, int n_in,
                              void* d_out, int out_size, void* d_ws, size_t ws_size,
                              hipStream_t stream) {
  const float* x  = (const float*)d_in[0];
  const float* Wq = (const float*)d_in[1];
  const float* bq = (const float*)d_in[2];
  const float* Wk = (const float*)d_in[3];
  const float* bk = (const float*)d_in[4];
  const float* Wv = (const float*)d_in[5];
  const float* bv = (const float*)d_in[6];
  float* out = (float*)d_out;

  _Float16* w16 = (_Float16*)d_ws;
  const size_t M1 = (size_t)1024 * 1024;
  _Float16* Qb = w16;                 //  0M .. 8M el (16 MB)
  _Float16* Kb = w16 + 8 * M1;        //  8M .. 16M
  _Float16* Vt = w16 + 16 * M1;       // 16M .. 24M  (V transposed [b][d][s])
  _Float16* xb = w16 + 24 * M1;       // 24M .. 32M  (dead after qkv_gemm)
  _Float16* Wb = w16 + 32 * M1;       // 32M .. 35M  (dead after qkv_gemm)
  _Float16* Pm = w16 + 24 * M1;       // packed tri P (17.8 MB), aliases xb
  float*    lsum = (float*)(w16 + 34 * M1);  // 32 KB row sums

  hipMemsetAsync(lsum, 0, NB * SEQ * sizeof(float), stream);
  cvt_all<<<dim3(512, 4), 256, 0, stream>>>(x, Wq, Wk, Wv, xb, Wb);
  qkv_gemm<<<dim3(64, 8, 3), 256, 0, stream>>>(xb, Wb, bq, bk, bv, Qb, Kb, Vt);
  qk_gemm<<<dim3(136, NB), 256, 0, stream>>>(Qb, Kb, Pm, lsum);
  pv_gemm<<<dim3(16, 8, NB), 256, 0, stream>>>(Pm, Vt, lsum, out);
}